// Round 4
// baseline (1147.368 us; speedup 1.0000x reference)
//
#include <hip/hip_runtime.h>
#include <math.h>

#define NROWS 16384
#define DDIM  1024
#define HIDD  4096
// IN_DIM = 4097 handled as K=4096 + last-row epilogue term

typedef __bf16 bf16;
typedef bf16 bf16x8 __attribute__((ext_vector_type(8)));
typedef bf16 bf16x4 __attribute__((ext_vector_type(4)));
typedef float f32x4 __attribute__((ext_vector_type(4)));
typedef float f32x16 __attribute__((ext_vector_type(16)));

__device__ __forceinline__ float gelu_erf(float x) {
  return 0.5f * x * (1.0f + erff(x * 0.70710678118654752f));
}

__device__ __forceinline__ void gld16(const bf16* g, bf16* l) {
  __builtin_amdgcn_global_load_lds(
      (const __attribute__((address_space(1))) void*)g,
      (__attribute__((address_space(3))) void*)l, 16, 0, 0);
}

// ---------------- elementwise cast fp32 -> bf16 (vector4) ----------------
__global__ __launch_bounds__(256) void cast_bf16_k(const float* __restrict__ in,
                                                   bf16* __restrict__ out) {
  size_t i = (size_t)blockIdx.x * blockDim.x + threadIdx.x;
  float4 v = ((const float4*)in)[i];
  bf16x4 o = {(bf16)v.x, (bf16)v.y, (bf16)v.z, (bf16)v.w};
  ((bf16x4*)out)[i] = o;
}

// ---------------- tiled transpose + cast: in[R][C] fp32 -> out[C][R] bf16 ----
__global__ __launch_bounds__(256) void transpose_cast_k(const float* __restrict__ in,
                                                        bf16* __restrict__ out,
                                                        int R, int C) {
  __shared__ float tile[32][33];
  int bx = blockIdx.x * 32, by = blockIdx.y * 32;
  int tx = threadIdx.x, ty = threadIdx.y;
  #pragma unroll
  for (int i = ty; i < 32; i += 8)
    tile[i][tx] = in[(size_t)(by + i) * C + bx + tx];
  __syncthreads();
  #pragma unroll
  for (int i = ty; i < 32; i += 8)
    out[(size_t)(bx + i) * R + by + tx] = (bf16)tile[tx][i];
}

// ---------------- fused row op: had/diff/s + LayerNorm -> x_bf16, s_ln -------
__global__ __launch_bounds__(256) void rowfuse_k(
    const float* __restrict__ zA, const float* __restrict__ zB,
    const bf16* __restrict__ t, const float* __restrict__ lng,
    const float* __restrict__ lnb, bf16* __restrict__ x,
    float* __restrict__ s_ln) {
  int row = blockIdx.x, tid = threadIdx.x;
  float4 a4 = ((const float4*)(zA + (size_t)row * DDIM))[tid];
  float4 b4 = ((const float4*)(zB + (size_t)row * DDIM))[tid];
  bf16x4 t4 = ((const bf16x4*)(t + (size_t)row * DDIM))[tid];
  float av[4] = {a4.x, a4.y, a4.z, a4.w};
  float bv[4] = {b4.x, b4.y, b4.z, b4.w};
  float hv[4], dv[4];
  float s1 = 0.f, s2 = 0.f, sd = 0.f;
  #pragma unroll
  for (int j = 0; j < 4; j++) {
    hv[j] = av[j] * bv[j];
    dv[j] = fabsf(av[j] - bv[j]);
    s1 += av[j] + bv[j] + hv[j] + dv[j];
    s2 += av[j]*av[j] + bv[j]*bv[j] + hv[j]*hv[j] + dv[j]*dv[j];
    sd += (float)t4[j] * bv[j];
  }
  #pragma unroll
  for (int off = 32; off > 0; off >>= 1) {
    s1 += __shfl_xor(s1, off, 64);
    s2 += __shfl_xor(s2, off, 64);
    sd += __shfl_xor(sd, off, 64);
  }
  __shared__ float red[3][4];
  int wave = tid >> 6;
  if ((tid & 63) == 0) { red[0][wave] = s1; red[1][wave] = s2; red[2][wave] = sd; }
  __syncthreads();
  s1 = red[0][0] + red[0][1] + red[0][2] + red[0][3];
  s2 = red[1][0] + red[1][1] + red[1][2] + red[1][3];
  float s = red[2][0] + red[2][1] + red[2][2] + red[2][3];
  const float inv = 1.0f / 4097.0f;
  float mu = (s1 + s) * inv;
  float var = (s2 + s * s) * inv - mu * mu;
  float rs = rsqrtf(var + 1e-5f);
  bf16* xr = x + (size_t)row * 4096;
  #define WRITE_SEG(si, vals)                                            \
  {                                                                      \
    float4 gg = ((const float4*)lng)[(si)*256 + tid];                    \
    float4 bb = ((const float4*)lnb)[(si)*256 + tid];                    \
    const float* gp = (const float*)&gg;                                 \
    const float* bp = (const float*)&bb;                                 \
    bf16x4 o;                                                            \
    _Pragma("unroll") for (int j = 0; j < 4; j++)                        \
        o[j] = (bf16)((vals[j] - mu) * rs * gp[j] + bp[j]);              \
    ((bf16x4*)xr)[(si)*256 + tid] = o;                                   \
  }
  WRITE_SEG(0, av)
  WRITE_SEG(1, bv)
  WRITE_SEG(2, hv)
  WRITE_SEG(3, dv)
  #undef WRITE_SEG
  if (tid == 0) s_ln[row] = (s - mu) * rs * lng[4096] + lnb[4096];
}

// ---------------- bf16 MFMA GEMM, 128x128 tile (EPI 0 and 2) ----------------
// EPI 0: store bf16 (t = zA@bilinear)
// EPI 2: v += b2[col]; gelu; store fp32 (out)
template <int EPI>
__global__ __launch_bounds__(256) void gemm_bt_k(
    const bf16* __restrict__ A, const bf16* __restrict__ B, int K, int Nout,
    void* __restrict__ Cout, const float* __restrict__ bias,
    const float* __restrict__ srow, const float* __restrict__ wlast) {
  __shared__ alignas(16) bf16 As[128 * 64];
  __shared__ alignas(16) bf16 Bs[128 * 64];
  const int tid = threadIdx.x;
  const int wave = tid >> 6, lane = tid & 63;
  const int wm = wave >> 1, wn = wave & 1;
  const int lrow = lane & 15, quad = lane >> 4;
  const size_t rowA0 = (size_t)blockIdx.y * 128;
  const size_t rowB0 = (size_t)blockIdx.x * 128;

  f32x4 acc[4][4] = {};

  const int lchunk = (tid & 7) ^ ((tid >> 3) & 7);
  const bf16* gA = A + (rowA0 + (tid >> 3)) * (size_t)K + lchunk * 8;
  const bf16* gB = B + (rowB0 + (tid >> 3)) * (size_t)K + lchunk * 8;

  for (int kb = 0; kb < K; kb += 64) {
    const bf16* pa = gA + kb;
    const bf16* pb = gB + kb;
    #pragma unroll
    for (int it = 0; it < 4; it++) {
      gld16(pa + (size_t)it * 32 * K, As + it * 2048 + wave * 512);
      gld16(pb + (size_t)it * 32 * K, Bs + it * 2048 + wave * 512);
    }
    __syncthreads();
    #pragma unroll
    for (int kk = 0; kk < 2; kk++) {
      const int cla = ((kk * 4 + quad) ^ (lrow & 7)) * 8;
      bf16x8 af[4], bfr[4];
      #pragma unroll
      for (int mi = 0; mi < 4; mi++)
        af[mi] = *(const bf16x8*)(As + (wm * 64 + mi * 16 + lrow) * 64 + cla);
      #pragma unroll
      for (int ni = 0; ni < 4; ni++)
        bfr[ni] = *(const bf16x8*)(Bs + (wn * 64 + ni * 16 + lrow) * 64 + cla);
      #pragma unroll
      for (int mi = 0; mi < 4; mi++)
        #pragma unroll
        for (int ni = 0; ni < 4; ni++)
          acc[mi][ni] = __builtin_amdgcn_mfma_f32_16x16x32_bf16(af[mi], bfr[ni], acc[mi][ni], 0, 0, 0);
    }
    __syncthreads();
  }

  const size_t ldc = (size_t)Nout;
  #pragma unroll
  for (int mi = 0; mi < 4; mi++) {
    size_t row = rowA0 + wm * 64 + mi * 16 + quad * 4;
    float srv[4];
    if (EPI == 1) {
      #pragma unroll
      for (int r = 0; r < 4; r++) srv[r] = srow[row + r];
    }
    #pragma unroll
    for (int ni = 0; ni < 4; ni++) {
      size_t col = rowB0 + wn * 64 + ni * 16 + lrow;
      float bvv = (EPI != 0) ? bias[col] : 0.0f;
      float wl = (EPI == 1) ? wlast[col] : 0.0f;
      #pragma unroll
      for (int r = 0; r < 4; r++) {
        float v = acc[mi][ni][r];
        if (EPI == 1) v += bvv + srv[r] * wl;
        if (EPI == 2) v += bvv;
        if (EPI != 0) v = gelu_erf(v);
        size_t idx = (row + r) * ldc + col;
        if (EPI == 2) ((float*)Cout)[idx] = v;
        else ((bf16*)Cout)[idx] = (bf16)v;
      }
    }
  }
}

// -------- 256x128-tile, 2-blocks/CU, ring-3, 32x32x16-MFMA GEMM (EPI1) ------
// Same structure/ledger as r3 (256 thr = 4 waves 2Mx2N, wave tile 128x64,
// BK=32 ring of 3, 72 KiB LDS -> 2 blocks/CU, vmcnt(6) once per tile), but
// fragments are 32x32x16 (4x2 frags/wave, 2 kk-steps): the 32x32 pipe runs
// ~4060 FLOP/cyc/CU vs 16x16's ~3378 (m119/m06), and MFMA inst count halves
// (16x 8-cyc ops vs 32x 4.85-cyc) -> fewer issue slots, coarser deps.
// LDS swizzle for 32x32 reads: phys 16B chunk p of row r holds logical chunk
// p^(r&3); fragment read (logical chunk c = kk*2 + (lane>>5)) hits all 4
// chunks across rows -> 8 dword-accesses/bank/inst (conflict-free minimum).
// Staged via pre-swizzled GLOBAL source (rule #21): thread t fetches logical
// chunk (t&3)^((t>>2)&3) so linear lane-contiguous LDS writes land swizzled.
// C/D map (m74/m101, HW-verified): col=lane&31, row=(reg&3)+8*(reg>>2)+4*hi.
// Ledger unchanged: tile j+2's 6 loads issue during tile j (4 A in phA, 2 B
// in phB); vmcnt(6) at phB drains tile j+1 => buffer (j+1)%3 ready. Tail
// stages wrap ko&(K-1) (never skipped => counts exact).
#define CFENCE asm volatile("" ::: "memory")
__global__ __launch_bounds__(256, 2) void gemm256x128_epi1_k(
    const bf16* __restrict__ A, const bf16* __restrict__ B, int K, int Nout,
    bf16* __restrict__ Cout, const float* __restrict__ bias,
    const float* __restrict__ srow, const float* __restrict__ wlast) {
  __shared__ alignas(16) bf16 As[3][8192];   // 3 x 256 rows x 32 k
  __shared__ alignas(16) bf16 Bs[3][4096];   // 3 x 128 rows x 32 k
  const int tid = threadIdx.x;
  const int wave = tid >> 6, lane = tid & 63;
  const int wm = wave >> 1, wn = wave & 1;
  const int l31 = lane & 31, hi = lane >> 5;
  // kk=0 logical chunk = hi; phys = (hi ^ (row&3)); row&3 == lane&3 for all
  // fragment rows (row = base + l31, base % 4 == 0). Element offset (x8).
  const int cs0 = ((hi ^ (lane & 3)) << 3);  // kk=1 offset: cs0 ^ 16

  // bijective 8x8-rectangle-per-XCD swizzle for the 32x32 grid (C=8192);
  // identity fallback otherwise (correctness never depends on the mapping).
  const int id = blockIdx.x;
  const int ncol = Nout >> 7;
  const int nrow = (int)(gridDim.x / ncol);
  int bxt, byt;
  if (ncol == 32 && nrow == 32) {
    const int xcd = id & 7, k = id >> 3;
    const int rect = k >> 6, pos = k & 63;
    byt = ((xcd >> 1) << 3) + (pos >> 3);
    bxt = ((xcd & 1) << 4) + (rect << 3) + (pos & 7);
  } else {
    bxt = id % ncol;
    byt = id / ncol;
  }
  const size_t rowA0 = (size_t)byt * 256;
  const size_t rowB0 = (size_t)bxt * 128;
  const int Kmask = K - 1;
  const size_t Ksz = (size_t)K;

  // staging: thread t -> row t>>2 (within 64-row slab), phys chunk t&3;
  // fetch logical chunk (t&3)^((t>>2)&3) (pre-swizzled source, rule #21)
  const int sq = (tid & 3) ^ ((tid >> 2) & 3);
  const bf16* gA = A + (rowA0 + (tid >> 2)) * Ksz + sq * 8;
  const bf16* gB = B + (rowB0 + (tid >> 2)) * Ksz + sq * 8;
  const int wofs = wave * 512;  // 64 lanes x 8 bf16 per wave per gld16

  f32x16 acc[4][2] = {};

#define STG_A3(rb, ko) { const bf16* s_ = gA + ((ko) & Kmask);           \
    gld16(s_,             &As[rb][0 * 2048 + wofs]);                     \
    gld16(s_ +  64 * Ksz, &As[rb][1 * 2048 + wofs]);                     \
    gld16(s_ + 128 * Ksz, &As[rb][2 * 2048 + wofs]);                     \
    gld16(s_ + 192 * Ksz, &As[rb][3 * 2048 + wofs]); }
#define STG_B3(rb, ko) { const bf16* s_ = gB + ((ko) & Kmask);           \
    gld16(s_,             &Bs[rb][0 * 2048 + wofs]);                     \
    gld16(s_ +  64 * Ksz, &Bs[rb][1 * 2048 + wofs]); }

  bf16x8 af[8], bfr[2];
  const int arow = wm * 128 + l31;   // + mi*32
  const int brow = wn * 64 + l31;    // + ni*32

#define LD_A32(rb) { _Pragma("unroll") for (int mi = 0; mi < 4; mi++) {  \
    af[mi*2+0] = *(const bf16x8*)(&As[rb][(arow + mi*32) * 32 + cs0]);        \
    af[mi*2+1] = *(const bf16x8*)(&As[rb][(arow + mi*32) * 32 + (cs0^16)]); } }
#define LD_B32(rb, ni) {                                                 \
    bfr[0] = *(const bf16x8*)(&Bs[rb][(brow + (ni)*32) * 32 + cs0]);     \
    bfr[1] = *(const bf16x8*)(&Bs[rb][(brow + (ni)*32) * 32 + (cs0^16)]); }
#define MFMA_N(ni) {                                                     \
    _Pragma("unroll") for (int mi = 0; mi < 4; mi++)                     \
      acc[mi][ni] = __builtin_amdgcn_mfma_f32_32x32x16_bf16(af[mi*2+0], bfr[0], acc[mi][ni], 0, 0, 0); \
    _Pragma("unroll") for (int mi = 0; mi < 4; mi++)                     \
      acc[mi][ni] = __builtin_amdgcn_mfma_f32_32x32x16_bf16(af[mi*2+1], bfr[1], acc[mi][ni], 0, 0, 0); }
#define TILE(rb, rs, ko) {                                               \
    LD_B32(rb, 0)                                                        \
    LD_A32(rb)                                                           \
    STG_A3(rs, ko)                                                       \
    CFENCE;                                                              \
    __builtin_amdgcn_s_barrier();                                        \
    CFENCE;                                                              \
    __builtin_amdgcn_s_setprio(1);                                       \
    MFMA_N(0)                                                            \
    __builtin_amdgcn_s_setprio(0);                                       \
    CFENCE;                                                              \
    __builtin_amdgcn_s_barrier();                                        \
    CFENCE;                                                              \
    LD_B32(rb, 1)                                                        \
    STG_B3(rs, ko)                                                       \
    asm volatile("s_waitcnt vmcnt(6)" ::: "memory");                     \
    CFENCE;                                                              \
    __builtin_amdgcn_s_barrier();                                        \
    CFENCE;                                                              \
    __builtin_amdgcn_s_setprio(1);                                       \
    MFMA_N(1)                                                            \
    __builtin_amdgcn_s_setprio(0);                                       \
    CFENCE;                                                              \
    __builtin_amdgcn_s_barrier();                                        \
    CFENCE; }

  // prologue: stage tiles 0,1 (12 loads); wait tile 0 (leave tile 1 in flight)
  STG_A3(0, 0)  STG_B3(0, 0)
  STG_A3(1, 32) STG_B3(1, 32)
  asm volatile("s_waitcnt vmcnt(6)" ::: "memory");
  __builtin_amdgcn_s_barrier();
  CFENCE;

  // K/32 = 128 tiles = 42 triples + 2 tail tiles (ring indices static)
  int kb = 64;
  #pragma unroll 1
  for (int i = 0; i < 42; ++i, kb += 96) {
    TILE(0, 2, kb)
    TILE(1, 0, kb + 32)
    TILE(2, 1, kb + 64)
  }
  TILE(0, 2, kb)        // tile 126; stage wraps to k=0 (dead, keeps counts)
  TILE(1, 0, kb + 32)   // tile 127; stage wraps to k=32 (dead)
  asm volatile("s_waitcnt vmcnt(0)" ::: "memory");
#undef TILE
#undef MFMA_N
#undef LD_B32
#undef LD_A32
#undef STG_B3
#undef STG_A3

  const size_t ldc = (size_t)Nout;
  float bvv[2], wl2[2];
  #pragma unroll
  for (int ni = 0; ni < 2; ni++) {
    size_t col = rowB0 + wn * 64 + ni * 32 + l31;
    bvv[ni] = bias[col];
    wl2[ni] = wlast[col];
  }
  #pragma unroll
  for (int mi = 0; mi < 4; mi++) {
    #pragma unroll
    for (int g = 0; g < 4; g++) {
      size_t row0 = rowA0 + wm * 128 + mi * 32 + g * 8 + hi * 4;
      float srv[4];
      #pragma unroll
      for (int r = 0; r < 4; r++) srv[r] = srow[row0 + r];
      #pragma unroll
      for (int ni = 0; ni < 2; ni++) {
        size_t col = rowB0 + wn * 64 + ni * 32 + l31;
        #pragma unroll
        for (int r = 0; r < 4; r++) {
          float v = acc[mi][ni][g * 4 + r] + bvv[ni] + srv[r] * wl2[ni];
          v = gelu_erf(v);
          Cout[(row0 + r) * ldc + col] = (bf16)v;
        }
      }
    }
  }
}

extern "C" void kernel_launch(void* const* d_in, const int* in_sizes, int n_in,
                              void* d_out, int out_size, void* d_ws, size_t ws_size,
                              hipStream_t stream) {
  const float* zA  = (const float*)d_in[0];
  const float* zB  = (const float*)d_in[1];
  const float* bil = (const float*)d_in[2];
  const float* lng = (const float*)d_in[3];
  const float* lnb = (const float*)d_in[4];
  const float* W1  = (const float*)d_in[5];
  const float* b1  = (const float*)d_in[6];
  const float* W2  = (const float*)d_in[7];
  const float* b2  = (const float*)d_in[8];
  float* out = (float*)d_out;

  // ---- workspace layout (adaptive row-chunking) ----
  char* ws = (char*)d_ws;
  const size_t SZ_BILT = (size_t)DDIM * DDIM * 2;        //  2 MiB
  const size_t SZ_W1T  = (size_t)4096 * 4096 * 2;        // 32 MiB
  const size_t SZ_W2T  = (size_t)DDIM * HIDD * 2;        //  8 MiB
  const size_t PERSIST = SZ_BILT + SZ_W1T + SZ_W2T;      // 42 MiB

  int C = 0;
  for (int cand = NROWS; cand >= 512; cand >>= 1) {
    size_t need = PERSIST + (size_t)16384 * cand + (size_t)4 * cand + 1024;
    if (need <= ws_size) { C = cand; break; }
  }
  if (C == 0) return;  // workspace hopelessly small — leave poison (fail loudly)

  bf16* bilT = (bf16*)ws;
  bf16* W1T  = (bf16*)(ws + SZ_BILT);
  bf16* W2T  = (bf16*)(ws + SZ_BILT + SZ_W1T);
  char* dyn  = ws + PERSIST;
  bf16*  r1    = (bf16*)dyn;                              // region1: zA_bf|t_bf -> h
  bf16*  zA_bf = r1;                                      // [C,1024] bf16
  bf16*  t_bf  = r1 + (size_t)C * 1024;                   // [C,1024] bf16
  bf16*  h_bf  = r1;                                      // [C,4096] bf16 (overlays after rowfuse)
  bf16*  x_bf  = (bf16*)(dyn + (size_t)8192 * C);         // [C,4096] bf16
  float* s_ln  = (float*)(dyn + (size_t)16384 * C);       // [C] fp32

  dim3 tb(32, 8);
  transpose_cast_k<<<dim3(DDIM / 32, DDIM / 32), tb, 0, stream>>>(bil, bilT, DDIM, DDIM);
  transpose_cast_k<<<dim3(HIDD / 32, 4096 / 32), tb, 0, stream>>>(W1, W1T, 4096, HIDD);
  transpose_cast_k<<<dim3(DDIM / 32, HIDD / 32), tb, 0, stream>>>(W2, W2T, HIDD, DDIM);

  for (int r0 = 0; r0 < NROWS; r0 += C) {
    const float* zAc = zA + (size_t)r0 * DDIM;
    const float* zBc = zB + (size_t)r0 * DDIM;

    // cast zA chunk -> bf16
    cast_bf16_k<<<(C * DDIM / 4) / 256, 256, 0, stream>>>(zAc, zA_bf);

    // t = zA @ bilinear   [C, DDIM]
    gemm_bt_k<0><<<dim3(DDIM / 128, C / 128), 256, 0, stream>>>(
        zA_bf, bilT, DDIM, DDIM, t_bf, nullptr, nullptr, nullptr);

    // had/diff/s + LayerNorm -> x_bf, s_ln
    rowfuse_k<<<C, 256, 0, stream>>>(zAc, zBc, t_bf, lng, lnb, x_bf, s_ln);

    // h = gelu(x @ W1 + b1 + s_ln*W1_last)  [C, HIDD]
    // 256x128 tiles, 256 threads, 2 blocks/CU, 32x32x16 MFMA
    gemm256x128_epi1_k<<<dim3((HIDD / 128) * (C / 256)), 256, 0, stream>>>(
        x_bf, W1T, 4096, HIDD, h_bf, b1, s_ln, W1 + (size_t)4096 * HIDD);

    // out = gelu(h @ W2 + b2)   [C, DDIM]
    gemm_bt_k<2><<<dim3(DDIM / 128, C / 128), 256, 0, stream>>>(
        h_bf, W2T, 4096, DDIM, out + (size_t)r0 * DDIM, b2, nullptr, nullptr);
  }
}